// Round 1
// baseline (141.156 us; speedup 1.0000x reference)
//
#include <hip/hip_runtime.h>

#define B_ 4
#define F_ 2
#define C_ 16
#define H_ 48
#define W_ 160
#define D_ 96
#define HW_ (H_*W_)

// Per-(b,f): P = (K @ T)[:3] rows (12 floats) + valid flag at [12].
__global__ __launch_bounds__(64) void mats_kernel(
    const float* __restrict__ poses, const float* __restrict__ Kmat,
    float* __restrict__ mats)
{
  int t = threadIdx.x;
  if (t >= B_*F_) return;
  int b = t / F_;
  const float* T  = poses + t*16;
  const float* Kb = Kmat + b*16;
  float sum = 0.f;
  #pragma unroll
  for (int i = 0; i < 16; ++i) sum += T[i];
  #pragma unroll
  for (int i = 0; i < 3; ++i) {
    #pragma unroll
    for (int j = 0; j < 4; ++j) {
      float v = 0.f;
      #pragma unroll
      for (int k = 0; k < 4; ++k) v += Kb[i*4+k] * T[k*4+j];
      mats[t*16 + i*4 + j] = v;
    }
  }
  mats[t*16 + 12] = (sum != 0.f) ? 1.f : 0.f;
}

// [nslice, C, HW] -> [nslice, HW, C]
__global__ __launch_bounds__(256) void transpose_kernel(
    const float* __restrict__ in, float* __restrict__ out, int total)
{
  int idx = blockIdx.x*256 + threadIdx.x;
  if (idx >= total) return;
  int hw = idx % HW_;
  int s  = idx / HW_;
  const float* src = in + (size_t)s * C_ * HW_ + hw;
  float r[C_];
  #pragma unroll
  for (int c = 0; c < C_; ++c) r[c] = src[(size_t)c * HW_];
  float4* o = reinterpret_cast<float4*>(out + (size_t)idx * C_);
  o[0] = make_float4(r[0],  r[1],  r[2],  r[3]);
  o[1] = make_float4(r[4],  r[5],  r[6],  r[7]);
  o[2] = make_float4(r[8],  r[9],  r[10], r[11]);
  o[3] = make_float4(r[12], r[13], r[14], r[15]);
}

// One thread per (b, d, hw). Writes pre-fill cost = sum_f diffs / (counts+1e-7).
__global__ __launch_bounds__(256) void cost_kernel(
    const float* __restrict__ curT, const float* __restrict__ lookT,
    const float* __restrict__ mats, const float* __restrict__ invK,
    const float* __restrict__ dbins, float* __restrict__ cost_pre)
{
  int idx = blockIdx.x*256 + threadIdx.x;
  int hw = idx % HW_;
  int rest = idx / HW_;
  int d = rest % D_;
  int b = rest / D_;
  int x = hw % W_, y = hw / W_;
  float out = 0.f;
  if (x >= 2 && x < W_-2 && y >= 2 && y < H_-2) {
    float depth = dbins[d];
    const float* iK = invK + b*16;
    float xf = (float)x, yf = (float)y;
    float r0 = iK[0]*xf + iK[1]*yf + iK[2];
    float r1 = iK[4]*xf + iK[5]*yf + iK[6];
    float r2 = iK[8]*xf + iK[9]*yf + iK[10];
    float p0 = depth*r0, p1 = depth*r1, p2 = depth*r2;
    const float4* cur4 = reinterpret_cast<const float4*>(curT + (size_t)(b*HW_ + hw)*C_);
    float4 cc0 = cur4[0], cc1 = cur4[1], cc2 = cur4[2], cc3 = cur4[3];
    float costsum = 0.f, cnt = 0.f;
    #pragma unroll
    for (int f = 0; f < F_; ++f) {
      const float* Mt = mats + (b*F_+f)*16;
      float camx = Mt[0]*p0 + Mt[1]*p1 + Mt[2] *p2 + Mt[3];
      float camy = Mt[4]*p0 + Mt[5]*p1 + Mt[6] *p2 + Mt[7];
      float camz = Mt[8]*p0 + Mt[9]*p1 + Mt[10]*p2 + Mt[11];
      float valid = Mt[12];
      float z  = camz + 1e-7f;
      float px = camx / z;
      float py = camy / z;
      // When the edge mask passes, all 4 bilinear taps are in-bounds:
      // px<=158 -> x0+1<=159<W; py<=46 -> y0+1<=47<H.
      if (valid != 0.f && px >= 2.f && px <= (float)(W_-2)
                       && py >= 2.f && py <= (float)(H_-2)) {
        float x0 = floorf(px), y0 = floorf(py);
        float fx = px - x0, fy = py - y0;
        int xi = (int)x0, yi = (int)y0;
        const float* base = lookT + ((size_t)(b*F_+f)*HW_ + yi*W_ + xi) * C_;
        const float4* t0 = reinterpret_cast<const float4*>(base);
        const float4* t1 = reinterpret_cast<const float4*>(base + W_*C_);
        float w00 = (1.f-fx)*(1.f-fy), w10 = fx*(1.f-fy);
        float w01 = (1.f-fx)*fy,       w11 = fx*fy;
        float s = 0.f;
        float4 cc[4] = {cc0, cc1, cc2, cc3};
        #pragma unroll
        for (int q = 0; q < 4; ++q) {
          float4 a00 = t0[q], a10 = t0[q+4];
          float4 a01 = t1[q], a11 = t1[q+4];
          float4 cv = cc[q];
          s += fabsf(w00*a00.x + w10*a10.x + w01*a01.x + w11*a11.x - cv.x);
          s += fabsf(w00*a00.y + w10*a10.y + w01*a01.y + w11*a11.y - cv.y);
          s += fabsf(w00*a00.z + w10*a10.z + w01*a01.z + w11*a11.z - cv.z);
          s += fabsf(w00*a00.w + w10*a10.w + w01*a01.w + w11*a11.w - cv.w);
        }
        float diffs = s * (1.f/16.f);
        costsum += diffs;
        cnt     += (diffs > 0.f) ? 1.f : 0.f;
      }
    }
    out = costsum / (cnt + 1e-7f);
  }
  cost_pre[idx] = out;
}

// One thread per (b, hw): max over D, then missing-fill in place.
__global__ __launch_bounds__(256) void finalize_kernel(
    float* __restrict__ cost, float* __restrict__ missing)
{
  int idx = blockIdx.x*256 + threadIdx.x;
  int hw = idx % HW_;
  int b  = idx / HW_;
  size_t base = (size_t)b * D_ * HW_ + hw;
  float mx = 0.f;  // cost values are >= 0
  for (int d = 0; d < D_; ++d)
    mx = fmaxf(mx, cost[base + (size_t)d*HW_]);
  for (int d = 0; d < D_; ++d) {
    size_t o = base + (size_t)d*HW_;
    float v = cost[o];
    float miss = (v == 0.f) ? 1.f : 0.f;
    cost[o]    = miss ? mx : v;
    missing[o] = miss;
  }
}

extern "C" void kernel_launch(void* const* d_in, const int* in_sizes, int n_in,
                              void* d_out, int out_size, void* d_ws, size_t ws_size,
                              hipStream_t stream) {
  const float* cur   = (const float*)d_in[0];
  const float* look  = (const float*)d_in[1];
  const float* poses = (const float*)d_in[2];
  const float* Km    = (const float*)d_in[3];
  const float* invK  = (const float*)d_in[4];
  const float* dbins = (const float*)d_in[5];

  float* out_cost = (float*)d_out;
  float* out_miss = out_cost + (size_t)B_*D_*HW_;

  char*  ws    = (char*)d_ws;
  float* mats  = (float*)ws;                                   // 128 floats
  float* curT  = (float*)(ws + 1024);                          // B*HW*C floats
  float* lookT = (float*)(ws + 1024 + (size_t)B_*HW_*C_*4);    // B*F*HW*C floats

  mats_kernel<<<1, 64, 0, stream>>>(poses, Km, mats);
  transpose_kernel<<<(B_*HW_)/256, 256, 0, stream>>>(cur, curT, B_*HW_);
  transpose_kernel<<<(B_*F_*HW_)/256, 256, 0, stream>>>(look, lookT, B_*F_*HW_);
  cost_kernel<<<(B_*D_*HW_)/256, 256, 0, stream>>>(curT, lookT, mats, invK, dbins, out_cost);
  finalize_kernel<<<(B_*HW_)/256, 256, 0, stream>>>(out_cost, out_miss);
}

// Round 2
// 108.779 us; speedup vs baseline: 1.2976x; 1.2976x over previous
//
#include <hip/hip_runtime.h>
#include <hip/hip_fp16.h>

#define B_ 4
#define F_ 2
#define C_ 16
#define H_ 48
#define W_ 160
#define D_ 96
#define HW_ (H_*W_)
#define DG_ 4
#define NDG_ (D_/DG_)     // 24
#define HWB_ (HW_/256)    // 30

// Fused prep: mats (block 0), cur transpose (f32), look transpose+fp16.
__global__ __launch_bounds__(256) void prep_kernel(
    const float* __restrict__ cur, const float* __restrict__ look,
    const float* __restrict__ poses, const float* __restrict__ Kmat,
    float* __restrict__ curT, __half* __restrict__ lookH,
    float* __restrict__ mats)
{
  int tid = threadIdx.x;
  int bid = blockIdx.x;
  if (bid == 0 && tid < B_*F_) {
    int t = tid, b = t / F_;
    const float* T  = poses + t*16;
    const float* Kb = Kmat + b*16;
    float sum = 0.f;
    #pragma unroll
    for (int i = 0; i < 16; ++i) sum += T[i];
    #pragma unroll
    for (int i = 0; i < 3; ++i) {
      #pragma unroll
      for (int j = 0; j < 4; ++j) {
        float v = 0.f;
        #pragma unroll
        for (int k = 0; k < 4; ++k) v += Kb[i*4+k] * T[k*4+j];
        mats[t*16 + i*4 + j] = v;
      }
    }
    mats[t*16 + 12] = (sum != 0.f) ? 1.f : 0.f;
  }
  int idx = bid*256 + tid;
  if (idx < B_*HW_) {
    int hw = idx % HW_, s = idx / HW_;
    const float* src = cur + (size_t)s*C_*HW_ + hw;
    float r[C_];
    #pragma unroll
    for (int c = 0; c < C_; ++c) r[c] = src[(size_t)c*HW_];
    float4* o = reinterpret_cast<float4*>(curT + (size_t)idx*C_);
    o[0] = make_float4(r[0],  r[1],  r[2],  r[3]);
    o[1] = make_float4(r[4],  r[5],  r[6],  r[7]);
    o[2] = make_float4(r[8],  r[9],  r[10], r[11]);
    o[3] = make_float4(r[12], r[13], r[14], r[15]);
  } else {
    int j = idx - B_*HW_;            // 0 .. B*F*HW-1
    int hw = j % HW_, s = j / HW_;
    const float* src = look + (size_t)s*C_*HW_ + hw;
    __half2 h[8];
    #pragma unroll
    for (int c = 0; c < 8; ++c)
      h[c] = __floats2half2_rn(src[(size_t)(2*c)*HW_], src[(size_t)(2*c+1)*HW_]);
    uint4* o = reinterpret_cast<uint4*>(lookH + (size_t)j*C_);
    o[0] = *reinterpret_cast<uint4*>(&h[0]);
    o[1] = *reinterpret_cast<uint4*>(&h[4]);
  }
}

// One thread per (b, dg, hw) covering DG_ consecutive depth bins.
__global__ __launch_bounds__(256) void cost_kernel(
    const float* __restrict__ curT, const __half* __restrict__ lookH,
    const float* __restrict__ mats, const float* __restrict__ invK,
    const float* __restrict__ dbins, float* __restrict__ cost_pre)
{
  int bid = blockIdx.x;
  int hw = (bid % HWB_)*256 + (int)threadIdx.x;   // block-uniform b, dg
  int rest = bid / HWB_;
  int dg = rest % NDG_;
  int b  = rest / NDG_;
  int x = hw % W_, y = hw / W_;
  float res[DG_] = {0.f, 0.f, 0.f, 0.f};
  if (x >= 2 && x < W_-2 && y >= 2 && y < H_-2) {
    const float* iK = invK + b*16;
    float xf = (float)x, yf = (float)y;
    float r0 = iK[0]*xf + iK[1]*yf + iK[2];
    float r1 = iK[4]*xf + iK[5]*yf + iK[6];
    float r2 = iK[8]*xf + iK[9]*yf + iK[10];
    float dep[DG_];
    #pragma unroll
    for (int dd = 0; dd < DG_; ++dd) dep[dd] = dbins[dg*DG_ + dd];
    const float4* cur4 = reinterpret_cast<const float4*>(curT + (size_t)(b*HW_ + hw)*C_);
    float cc[C_];
    #pragma unroll
    for (int q = 0; q < 4; ++q) {
      float4 v = cur4[q];
      cc[4*q] = v.x; cc[4*q+1] = v.y; cc[4*q+2] = v.z; cc[4*q+3] = v.w;
    }
    float costsum[DG_] = {0,0,0,0}, cnt[DG_] = {0,0,0,0};
    #pragma unroll
    for (int f = 0; f < F_; ++f) {
      const float* Mt = mats + (b*F_+f)*16;
      float M0=Mt[0], M1=Mt[1], M2 =Mt[2],  M3 =Mt[3];
      float M4=Mt[4], M5=Mt[5], M6 =Mt[6],  M7 =Mt[7];
      float M8=Mt[8], M9=Mt[9], M10=Mt[10], M11=Mt[11];
      float valid = Mt[12];
      #pragma unroll
      for (int dd = 0; dd < DG_; ++dd) {
        float p0 = dep[dd]*r0, p1 = dep[dd]*r1, p2 = dep[dd]*r2;
        float camx = M0*p0 + M1*p1 + M2 *p2 + M3;
        float camy = M4*p0 + M5*p1 + M6 *p2 + M7;
        float camz = M8*p0 + M9*p1 + M10*p2 + M11;
        float z  = camz + 1e-7f;
        float px = camx / z;
        float py = camy / z;
        bool ok = (valid != 0.f) && (px >= 2.f) && (px <= (float)(W_-2))
                                 && (py >= 2.f) && (py <= (float)(H_-2));
        float x0 = floorf(px), y0 = floorf(py);
        float fx = px - x0, fy = py - y0;
        // clamp so !ok lanes still issue valid, convergent loads
        fx = fminf(fmaxf(fx, 0.f), 1.f);
        fy = fminf(fmaxf(fy, 0.f), 1.f);
        int xi = min(max((int)x0, 0), W_-2);
        int yi = min(max((int)y0, 0), H_-2);
        const __half* base = lookH + ((size_t)((b*F_+f)*HW_) + yi*W_ + xi)*C_;
        const uint4* rr0 = reinterpret_cast<const uint4*>(base);
        const uint4* rr1 = reinterpret_cast<const uint4*>(base + W_*C_);
        uint4 q00a = rr0[0], q00b = rr0[1], q10a = rr0[2], q10b = rr0[3];
        uint4 q01a = rr1[0], q01b = rr1[1], q11a = rr1[2], q11b = rr1[3];
        float w00 = (1.f-fx)*(1.f-fy), w10 = fx*(1.f-fy);
        float w01 = (1.f-fx)*fy,       w11 = fx*fy;
        const __half2* h00a = reinterpret_cast<const __half2*>(&q00a);
        const __half2* h10a = reinterpret_cast<const __half2*>(&q10a);
        const __half2* h01a = reinterpret_cast<const __half2*>(&q01a);
        const __half2* h11a = reinterpret_cast<const __half2*>(&q11a);
        const __half2* h00b = reinterpret_cast<const __half2*>(&q00b);
        const __half2* h10b = reinterpret_cast<const __half2*>(&q10b);
        const __half2* h01b = reinterpret_cast<const __half2*>(&q01b);
        const __half2* h11b = reinterpret_cast<const __half2*>(&q11b);
        float s = 0.f;
        #pragma unroll
        for (int i = 0; i < 4; ++i) {
          float2 a00 = __half22float2(h00a[i]);
          float2 a10 = __half22float2(h10a[i]);
          float2 a01 = __half22float2(h01a[i]);
          float2 a11 = __half22float2(h11a[i]);
          float vx = w00*a00.x + w10*a10.x + w01*a01.x + w11*a11.x;
          float vy = w00*a00.y + w10*a10.y + w01*a01.y + w11*a11.y;
          s += fabsf(vx - cc[2*i]);
          s += fabsf(vy - cc[2*i+1]);
        }
        #pragma unroll
        for (int i = 0; i < 4; ++i) {
          float2 a00 = __half22float2(h00b[i]);
          float2 a10 = __half22float2(h10b[i]);
          float2 a01 = __half22float2(h01b[i]);
          float2 a11 = __half22float2(h11b[i]);
          float vx = w00*a00.x + w10*a10.x + w01*a01.x + w11*a11.x;
          float vy = w00*a00.y + w10*a10.y + w01*a01.y + w11*a11.y;
          s += fabsf(vx - cc[8+2*i]);
          s += fabsf(vy - cc[8+2*i+1]);
        }
        float diffs = s * (1.f/16.f);
        diffs = ok ? diffs : 0.f;
        costsum[dd] += diffs;
        cnt[dd]     += (diffs > 0.f) ? 1.f : 0.f;
      }
    }
    #pragma unroll
    for (int dd = 0; dd < DG_; ++dd) res[dd] = costsum[dd] / (cnt[dd] + 1e-7f);
  }
  #pragma unroll
  for (int dd = 0; dd < DG_; ++dd)
    cost_pre[((size_t)(b*D_) + dg*DG_ + dd)*HW_ + hw] = res[dd];
}

// One thread per (b, hw): max over D, then missing-fill in place.
__global__ __launch_bounds__(256) void finalize_kernel(
    float* __restrict__ cost, float* __restrict__ missing)
{
  int idx = blockIdx.x*256 + threadIdx.x;
  int hw = idx % HW_;
  int b  = idx / HW_;
  size_t base = (size_t)b * D_ * HW_ + hw;
  float mx = 0.f;  // cost values are >= 0
  #pragma unroll 4
  for (int d = 0; d < D_; ++d)
    mx = fmaxf(mx, cost[base + (size_t)d*HW_]);
  #pragma unroll 4
  for (int d = 0; d < D_; ++d) {
    size_t o = base + (size_t)d*HW_;
    float v = cost[o];
    float miss = (v == 0.f) ? 1.f : 0.f;
    cost[o]    = miss ? mx : v;
    missing[o] = miss;
  }
}

extern "C" void kernel_launch(void* const* d_in, const int* in_sizes, int n_in,
                              void* d_out, int out_size, void* d_ws, size_t ws_size,
                              hipStream_t stream) {
  const float* cur   = (const float*)d_in[0];
  const float* look  = (const float*)d_in[1];
  const float* poses = (const float*)d_in[2];
  const float* Km    = (const float*)d_in[3];
  const float* invK  = (const float*)d_in[4];
  const float* dbins = (const float*)d_in[5];

  float* out_cost = (float*)d_out;
  float* out_miss = out_cost + (size_t)B_*D_*HW_;

  char*   ws    = (char*)d_ws;
  float*  mats  = (float*)ws;                                      // 128 floats
  float*  curT  = (float*)(ws + 1024);                             // B*HW*C f32
  __half* lookH = (__half*)(ws + 1024 + (size_t)B_*HW_*C_*4);      // B*F*HW*C f16

  prep_kernel<<<(B_*HW_ + B_*F_*HW_)/256, 256, 0, stream>>>(
      cur, look, poses, Km, curT, lookH, mats);
  cost_kernel<<<B_*NDG_*HWB_, 256, 0, stream>>>(
      curT, lookH, mats, invK, dbins, out_cost);
  finalize_kernel<<<(B_*HW_)/256, 256, 0, stream>>>(out_cost, out_miss);
}

// Round 3
// 67.653 us; speedup vs baseline: 2.0865x; 1.6079x over previous
//
#include <hip/hip_runtime.h>
#include <hip/hip_fp16.h>

#define B_ 4
#define F_ 2
#define C_ 16
#define H_ 48
#define W_ 160
#define D_ 96
#define HW_ (H_*W_)
#define DG_ 4
#define NDG_ (D_/DG_)     // 24
#define HWB_ (HW_/256)    // 30

// Fused prep: mats (block 0), cur transpose+fp16, look transpose+fp16.
__global__ __launch_bounds__(256) void prep_kernel(
    const float* __restrict__ cur, const float* __restrict__ look,
    const float* __restrict__ poses, const float* __restrict__ Kmat,
    __half* __restrict__ curH, __half* __restrict__ lookH,
    float* __restrict__ mats)
{
  int tid = threadIdx.x;
  int bid = blockIdx.x;
  if (bid == 0 && tid < B_*F_) {
    int t = tid, b = t / F_;
    const float* T  = poses + t*16;
    const float* Kb = Kmat + b*16;
    float sum = 0.f;
    #pragma unroll
    for (int i = 0; i < 16; ++i) sum += T[i];
    #pragma unroll
    for (int i = 0; i < 3; ++i) {
      #pragma unroll
      for (int j = 0; j < 4; ++j) {
        float v = 0.f;
        #pragma unroll
        for (int k = 0; k < 4; ++k) v += Kb[i*4+k] * T[k*4+j];
        mats[t*16 + i*4 + j] = v;
      }
    }
    mats[t*16 + 12] = (sum != 0.f) ? 1.f : 0.f;
  }
  int idx = bid*256 + tid;
  const float* src;
  __half* dst;
  if (idx < B_*HW_) {
    int hw = idx % HW_, s = idx / HW_;
    src = cur + (size_t)s*C_*HW_ + hw;
    dst = curH + (size_t)idx*C_;
  } else {
    int j = idx - B_*HW_;            // 0 .. B*F*HW-1
    int hw = j % HW_, s = j / HW_;
    src = look + (size_t)s*C_*HW_ + hw;
    dst = lookH + (size_t)j*C_;
  }
  __half2 h[8];
  #pragma unroll
  for (int c = 0; c < 8; ++c)
    h[c] = __floats2half2_rn(src[(size_t)(2*c)*HW_], src[(size_t)(2*c+1)*HW_]);
  uint4* o = reinterpret_cast<uint4*>(dst);
  o[0] = *reinterpret_cast<uint4*>(&h[0]);
  o[1] = *reinterpret_cast<uint4*>(&h[4]);
}

// One thread per (b, dg, hw) covering DG_ consecutive depth bins.
// All interpolation math in packed fp16.
__global__ __launch_bounds__(256, 4) void cost_kernel(
    const __half* __restrict__ curH, const __half* __restrict__ lookH,
    const float* __restrict__ mats, const float* __restrict__ invK,
    const float* __restrict__ dbins, float* __restrict__ cost_pre)
{
  int bid = blockIdx.x;
  int hw = (bid % HWB_)*256 + (int)threadIdx.x;   // block-uniform b, dg
  int rest = bid / HWB_;
  int dg = rest % NDG_;
  int b  = rest / NDG_;
  int x = hw % W_, y = hw / W_;
  float res[DG_] = {0.f, 0.f, 0.f, 0.f};
  if (x >= 2 && x < W_-2 && y >= 2 && y < H_-2) {
    const float* iK = invK + b*16;
    float xf = (float)x, yf = (float)y;
    float r0 = iK[0]*xf + iK[1]*yf + iK[2];
    float r1 = iK[4]*xf + iK[5]*yf + iK[6];
    float r2 = iK[8]*xf + iK[9]*yf + iK[10];
    float dep[DG_];
    #pragma unroll
    for (int dd = 0; dd < DG_; ++dd) dep[dd] = dbins[dg*DG_ + dd];
    // current feats as 8 half2
    uint4 ccq0, ccq1;
    {
      const uint4* cur4 = reinterpret_cast<const uint4*>(curH + (size_t)(b*HW_ + hw)*C_);
      ccq0 = cur4[0]; ccq1 = cur4[1];
    }
    __half2 cc2[8];
    *reinterpret_cast<uint4*>(&cc2[0]) = ccq0;
    *reinterpret_cast<uint4*>(&cc2[4]) = ccq1;

    float costsum[DG_] = {0,0,0,0}, cnt[DG_] = {0,0,0,0};
    #pragma unroll
    for (int f = 0; f < F_; ++f) {
      const float* Mt = mats + (b*F_+f)*16;
      float M0=Mt[0], M1=Mt[1], M2 =Mt[2],  M3 =Mt[3];
      float M4=Mt[4], M5=Mt[5], M6 =Mt[6],  M7 =Mt[7];
      float M8=Mt[8], M9=Mt[9], M10=Mt[10], M11=Mt[11];
      float valid = Mt[12];
      #pragma unroll
      for (int dd = 0; dd < DG_; ++dd) {
        float p0 = dep[dd]*r0, p1 = dep[dd]*r1, p2 = dep[dd]*r2;
        float camx = M0*p0 + M1*p1 + M2 *p2 + M3;
        float camy = M4*p0 + M5*p1 + M6 *p2 + M7;
        float camz = M8*p0 + M9*p1 + M10*p2 + M11;
        float z  = camz + 1e-7f;
        float px = camx / z;
        float py = camy / z;
        bool ok = (valid != 0.f) && (px >= 2.f) && (px <= (float)(W_-2))
                                 && (py >= 2.f) && (py <= (float)(H_-2));
        float x0 = floorf(px), y0 = floorf(py);
        float fx = px - x0, fy = py - y0;
        fx = fminf(fmaxf(fx, 0.f), 1.f);
        fy = fminf(fmaxf(fy, 0.f), 1.f);
        int xi = min(max((int)x0, 0), W_-2);
        int yi = min(max((int)y0, 0), H_-2);
        const __half* base = lookH + ((size_t)((b*F_+f)*HW_) + yi*W_ + xi)*C_;
        const uint4* rr0 = reinterpret_cast<const uint4*>(base);
        const uint4* rr1 = reinterpret_cast<const uint4*>(base + W_*C_);
        // q0[0..1]=pix(y0,x0), q0[2..3]=pix(y0,x0+1) — 64B contiguous; same row below.
        uint4 q0[4], q1[4];
        #pragma unroll
        for (int i = 0; i < 4; ++i) q0[i] = rr0[i];
        #pragma unroll
        for (int i = 0; i < 4; ++i) q1[i] = rr1[i];
        float w00 = (1.f-fx)*(1.f-fy), w10 = fx*(1.f-fy);
        float w01 = (1.f-fx)*fy,       w11 = fx*fy;
        __half2 w00h = __float2half2_rn(w00);
        __half2 w10h = __float2half2_rn(w10);
        __half2 w01h = __float2half2_rn(w01);
        __half2 w11h = __float2half2_rn(w11);
        const __half2* a00 = reinterpret_cast<const __half2*>(&q0[0]);
        const __half2* a10 = reinterpret_cast<const __half2*>(&q0[2]);
        const __half2* a01 = reinterpret_cast<const __half2*>(&q1[0]);
        const __half2* a11 = reinterpret_cast<const __half2*>(&q1[2]);
        __half2 acc0 = __float2half2_rn(0.f);
        __half2 acc1 = __float2half2_rn(0.f);
        #pragma unroll
        for (int i = 0; i < 8; ++i) {
          __half2 v = __hmul2(w00h, a00[i]);
          v = __hfma2(w10h, a10[i], v);
          v = __hfma2(w01h, a01[i], v);
          v = __hfma2(w11h, a11[i], v);
          __half2 dsub = __habs2(__hsub2(v, cc2[i]));
          if (i & 1) acc1 = __hadd2(acc1, dsub);
          else       acc0 = __hadd2(acc0, dsub);
        }
        float2 f0 = __half22float2(acc0);
        float2 f1 = __half22float2(acc1);
        float s = (f0.x + f0.y) + (f1.x + f1.y);
        float diffs = s * (1.f/16.f);
        diffs = ok ? diffs : 0.f;
        costsum[dd] += diffs;
        cnt[dd]     += (diffs > 0.f) ? 1.f : 0.f;
      }
    }
    #pragma unroll
    for (int dd = 0; dd < DG_; ++dd) res[dd] = costsum[dd] / (cnt[dd] + 1e-7f);
  }
  #pragma unroll
  for (int dd = 0; dd < DG_; ++dd)
    cost_pre[((size_t)(b*D_) + dg*DG_ + dd)*HW_ + hw] = res[dd];
}

// One thread per (b, hw): max over D, then missing-fill in place.
__global__ __launch_bounds__(256) void finalize_kernel(
    float* __restrict__ cost, float* __restrict__ missing)
{
  int idx = blockIdx.x*256 + threadIdx.x;
  int hw = idx % HW_;
  int b  = idx / HW_;
  size_t base = (size_t)b * D_ * HW_ + hw;
  float mx = 0.f;  // cost values are >= 0
  #pragma unroll 4
  for (int d = 0; d < D_; ++d)
    mx = fmaxf(mx, cost[base + (size_t)d*HW_]);
  #pragma unroll 4
  for (int d = 0; d < D_; ++d) {
    size_t o = base + (size_t)d*HW_;
    float v = cost[o];
    float miss = (v == 0.f) ? 1.f : 0.f;
    cost[o]    = miss ? mx : v;
    missing[o] = miss;
  }
}

extern "C" void kernel_launch(void* const* d_in, const int* in_sizes, int n_in,
                              void* d_out, int out_size, void* d_ws, size_t ws_size,
                              hipStream_t stream) {
  const float* cur   = (const float*)d_in[0];
  const float* look  = (const float*)d_in[1];
  const float* poses = (const float*)d_in[2];
  const float* Km    = (const float*)d_in[3];
  const float* invK  = (const float*)d_in[4];
  const float* dbins = (const float*)d_in[5];

  float* out_cost = (float*)d_out;
  float* out_miss = out_cost + (size_t)B_*D_*HW_;

  char*   ws    = (char*)d_ws;
  float*  mats  = (float*)ws;                                       // 128 floats
  __half* curH  = (__half*)(ws + 1024);                             // B*HW*C f16
  __half* lookH = (__half*)(ws + 1024 + (size_t)B_*HW_*C_*2);       // B*F*HW*C f16

  prep_kernel<<<(B_*HW_ + B_*F_*HW_)/256, 256, 0, stream>>>(
      cur, look, poses, Km, curH, lookH, mats);
  cost_kernel<<<B_*NDG_*HWB_, 256, 0, stream>>>(
      curH, lookH, mats, invK, dbins, out_cost);
  finalize_kernel<<<(B_*HW_)/256, 256, 0, stream>>>(out_cost, out_miss);
}

// Round 4
// 53.086 us; speedup vs baseline: 2.6590x; 1.2744x over previous
//
#include <hip/hip_runtime.h>
#include <hip/hip_fp16.h>

#define B_ 4
#define F_ 2
#define C_ 16
#define H_ 48
#define W_ 160
#define D_ 96
#define HW_ (H_*W_)
#define PIX_ 32            // pixels per block
#define GRP_ 8             // depth groups per block (PIX_*GRP_ = 256 threads)
#define BINS_ (D_/GRP_)    // 12 bins per group
#define NCHUNK_ (HW_/PIX_) // 240

// Fused prep: mats (block 0), cur transpose+fp16, look transpose+fp16.
__global__ __launch_bounds__(256) void prep_kernel(
    const float* __restrict__ cur, const float* __restrict__ look,
    const float* __restrict__ poses, const float* __restrict__ Kmat,
    __half* __restrict__ curH, __half* __restrict__ lookH,
    float* __restrict__ mats)
{
  int tid = threadIdx.x;
  int bid = blockIdx.x;
  if (bid == 0 && tid < B_*F_) {
    int t = tid, b = t / F_;
    const float* T  = poses + t*16;
    const float* Kb = Kmat + b*16;
    float sum = 0.f;
    #pragma unroll
    for (int i = 0; i < 16; ++i) sum += T[i];
    #pragma unroll
    for (int i = 0; i < 3; ++i) {
      #pragma unroll
      for (int j = 0; j < 4; ++j) {
        float v = 0.f;
        #pragma unroll
        for (int k = 0; k < 4; ++k) v += Kb[i*4+k] * T[k*4+j];
        mats[t*16 + i*4 + j] = v;
      }
    }
    mats[t*16 + 12] = (sum != 0.f) ? 1.f : 0.f;
  }
  int idx = bid*256 + tid;
  const float* src;
  __half* dst;
  if (idx < B_*HW_) {
    int hw = idx % HW_, s = idx / HW_;
    src = cur + (size_t)s*C_*HW_ + hw;
    dst = curH + (size_t)idx*C_;
  } else {
    int j = idx - B_*HW_;            // 0 .. B*F*HW-1
    int hw = j % HW_, s = j / HW_;
    src = look + (size_t)s*C_*HW_ + hw;
    dst = lookH + (size_t)j*C_;
  }
  __half2 h[8];
  #pragma unroll
  for (int c = 0; c < 8; ++c)
    h[c] = __floats2half2_rn(src[(size_t)(2*c)*HW_], src[(size_t)(2*c+1)*HW_]);
  uint4* o = reinterpret_cast<uint4*>(dst);
  o[0] = *reinterpret_cast<uint4*>(&h[0]);
  o[1] = *reinterpret_cast<uint4*>(&h[4]);
}

// Fused cost + finalize. Block = 32 pixels x 8 depth-groups (12 bins each).
// Each thread: compute its 12 bins (2 frames each), write pre-fill cost,
// LDS-reduce per-pixel max over groups, then re-read + missing-fill.
__global__ __launch_bounds__(256, 3) void fused_kernel(
    const __half* __restrict__ curH, const __half* __restrict__ lookH,
    const float* __restrict__ mats, const float* __restrict__ invK,
    const float* __restrict__ dbins,
    float* __restrict__ cost, float* __restrict__ missing)
{
  int tid = threadIdx.x;
  int pix = tid & (PIX_-1);
  int grp = tid >> 5;                 // 0..7
  int bid = blockIdx.x;
  int chunk = bid % NCHUNK_;
  int b = bid / NCHUNK_;
  int hw = chunk*PIX_ + pix;
  int x = hw % W_, y = hw / W_;
  size_t obase = ((size_t)(b*D_ + grp*BINS_))*HW_ + hw;

  float lmax = 0.f;
  bool interior = (x >= 2 && x < W_-2 && y >= 2 && y < H_-2);
  if (interior) {
    const float* iK = invK + b*16;
    float xf = (float)x, yf = (float)y;
    float r0 = iK[0]*xf + iK[1]*yf + iK[2];
    float r1 = iK[4]*xf + iK[5]*yf + iK[6];
    float r2 = iK[8]*xf + iK[9]*yf + iK[10];
    __half2 cc2[8];
    {
      const uint4* cur4 = reinterpret_cast<const uint4*>(curH + (size_t)(b*HW_ + hw)*C_);
      *reinterpret_cast<uint4*>(&cc2[0]) = cur4[0];
      *reinterpret_cast<uint4*>(&cc2[4]) = cur4[1];
    }
    #pragma unroll 4
    for (int dd = 0; dd < BINS_; ++dd) {
      float dep = dbins[grp*BINS_ + dd];
      float p0 = dep*r0, p1 = dep*r1, p2 = dep*r2;
      float costsum = 0.f, cnt = 0.f;
      #pragma unroll
      for (int f = 0; f < F_; ++f) {
        const float* Mt = mats + (b*F_+f)*16;
        float camx = Mt[0]*p0 + Mt[1]*p1 + Mt[2] *p2 + Mt[3];
        float camy = Mt[4]*p0 + Mt[5]*p1 + Mt[6] *p2 + Mt[7];
        float camz = Mt[8]*p0 + Mt[9]*p1 + Mt[10]*p2 + Mt[11];
        float valid = Mt[12];
        float z  = camz + 1e-7f;
        float px = camx / z;
        float py = camy / z;
        bool ok = (valid != 0.f) && (px >= 2.f) && (px <= (float)(W_-2))
                                 && (py >= 2.f) && (py <= (float)(H_-2));
        float x0 = floorf(px), y0 = floorf(py);
        float fx = px - x0, fy = py - y0;
        fx = fminf(fmaxf(fx, 0.f), 1.f);
        fy = fminf(fmaxf(fy, 0.f), 1.f);
        int xi = min(max((int)x0, 0), W_-2);
        int yi = min(max((int)y0, 0), H_-2);
        const __half* base = lookH + ((size_t)((b*F_+f)*HW_) + yi*W_ + xi)*C_;
        const uint4* rr0 = reinterpret_cast<const uint4*>(base);
        const uint4* rr1 = reinterpret_cast<const uint4*>(base + W_*C_);
        uint4 q0[4], q1[4];
        #pragma unroll
        for (int i = 0; i < 4; ++i) q0[i] = rr0[i];
        #pragma unroll
        for (int i = 0; i < 4; ++i) q1[i] = rr1[i];
        float w00 = (1.f-fx)*(1.f-fy), w10 = fx*(1.f-fy);
        float w01 = (1.f-fx)*fy,       w11 = fx*fy;
        __half2 w00h = __float2half2_rn(w00);
        __half2 w10h = __float2half2_rn(w10);
        __half2 w01h = __float2half2_rn(w01);
        __half2 w11h = __float2half2_rn(w11);
        const __half2* a00 = reinterpret_cast<const __half2*>(&q0[0]);
        const __half2* a10 = reinterpret_cast<const __half2*>(&q0[2]);
        const __half2* a01 = reinterpret_cast<const __half2*>(&q1[0]);
        const __half2* a11 = reinterpret_cast<const __half2*>(&q1[2]);
        __half2 acc0 = __float2half2_rn(0.f);
        __half2 acc1 = __float2half2_rn(0.f);
        #pragma unroll
        for (int i = 0; i < 8; ++i) {
          __half2 v = __hmul2(w00h, a00[i]);
          v = __hfma2(w10h, a10[i], v);
          v = __hfma2(w01h, a01[i], v);
          v = __hfma2(w11h, a11[i], v);
          __half2 dsub = __habs2(__hsub2(v, cc2[i]));
          if (i & 1) acc1 = __hadd2(acc1, dsub);
          else       acc0 = __hadd2(acc0, dsub);
        }
        float2 f0 = __half22float2(acc0);
        float2 f1 = __half22float2(acc1);
        float s = (f0.x + f0.y) + (f1.x + f1.y);
        float diffs = s * (1.f/16.f);
        diffs = ok ? diffs : 0.f;
        costsum += diffs;
        cnt     += (diffs > 0.f) ? 1.f : 0.f;
      }
      float r = costsum / (cnt + 1e-7f);
      cost[obase + (size_t)dd*HW_] = r;     // pre-fill value
      lmax = fmaxf(lmax, r);
    }
  } else {
    #pragma unroll 4
    for (int dd = 0; dd < BINS_; ++dd)
      cost[obase + (size_t)dd*HW_] = 0.f;
  }

  // per-pixel max over the 8 depth-groups
  __shared__ float lmaxs[GRP_][PIX_];
  lmaxs[grp][pix] = lmax;
  __syncthreads();
  float pmax = lmaxs[0][pix];
  #pragma unroll
  for (int g = 1; g < GRP_; ++g) pmax = fmaxf(pmax, lmaxs[g][pix]);

  // missing-fill (re-read own writes; L2-hot, coalesced)
  #pragma unroll 4
  for (int dd = 0; dd < BINS_; ++dd) {
    size_t o = obase + (size_t)dd*HW_;
    float v = cost[o];
    float miss = (v == 0.f) ? 1.f : 0.f;
    cost[o]    = miss ? pmax : v;
    missing[o] = miss;
  }
}

extern "C" void kernel_launch(void* const* d_in, const int* in_sizes, int n_in,
                              void* d_out, int out_size, void* d_ws, size_t ws_size,
                              hipStream_t stream) {
  const float* cur   = (const float*)d_in[0];
  const float* look  = (const float*)d_in[1];
  const float* poses = (const float*)d_in[2];
  const float* Km    = (const float*)d_in[3];
  const float* invK  = (const float*)d_in[4];
  const float* dbins = (const float*)d_in[5];

  float* out_cost = (float*)d_out;
  float* out_miss = out_cost + (size_t)B_*D_*HW_;

  char*   ws    = (char*)d_ws;
  float*  mats  = (float*)ws;                                       // 128 floats
  __half* curH  = (__half*)(ws + 1024);                             // B*HW*C f16
  __half* lookH = (__half*)(ws + 1024 + (size_t)B_*HW_*C_*2);       // B*F*HW*C f16

  prep_kernel<<<(B_*HW_ + B_*F_*HW_)/256, 256, 0, stream>>>(
      cur, look, poses, Km, curH, lookH, mats);
  fused_kernel<<<B_*NCHUNK_, 256, 0, stream>>>(
      curH, lookH, mats, invK, dbins, out_cost, out_miss);
}

// Round 5
// 41.629 us; speedup vs baseline: 3.3908x; 1.2752x over previous
//
#include <hip/hip_runtime.h>
#include <hip/hip_fp16.h>

#define B_ 4
#define F_ 2
#define C_ 16
#define H_ 48
#define W_ 160
#define D_ 96
#define HW_ (H_*W_)
#define PIX_ 32            // pixels per block
#define GRP_ 8             // depth groups per block (PIX_*GRP_ = 256 threads)
#define BINS_ (D_/GRP_)    // 12 bins per group
#define NCHUNK_ (HW_/PIX_) // 240

// Fused prep: mats (block 0), cur transpose+fp16, look transpose+fp16.
__global__ __launch_bounds__(256) void prep_kernel(
    const float* __restrict__ cur, const float* __restrict__ look,
    const float* __restrict__ poses, const float* __restrict__ Kmat,
    __half* __restrict__ curH, __half* __restrict__ lookH,
    float* __restrict__ mats)
{
  int tid = threadIdx.x;
  int bid = blockIdx.x;
  if (bid == 0 && tid < B_*F_) {
    int t = tid, b = t / F_;
    const float* T  = poses + t*16;
    const float* Kb = Kmat + b*16;
    float sum = 0.f;
    #pragma unroll
    for (int i = 0; i < 16; ++i) sum += T[i];
    #pragma unroll
    for (int i = 0; i < 3; ++i) {
      #pragma unroll
      for (int j = 0; j < 4; ++j) {
        float v = 0.f;
        #pragma unroll
        for (int k = 0; k < 4; ++k) v += Kb[i*4+k] * T[k*4+j];
        mats[t*16 + i*4 + j] = v;
      }
    }
    mats[t*16 + 12] = (sum != 0.f) ? 1.f : 0.f;
  }
  int idx = bid*256 + tid;
  const float* src;
  __half* dst;
  if (idx < B_*HW_) {
    int hw = idx % HW_, s = idx / HW_;
    src = cur + (size_t)s*C_*HW_ + hw;
    dst = curH + (size_t)idx*C_;
  } else {
    int j = idx - B_*HW_;            // 0 .. B*F*HW-1
    int hw = j % HW_, s = j / HW_;
    src = look + (size_t)s*C_*HW_ + hw;
    dst = lookH + (size_t)j*C_;
  }
  __half2 h[8];
  #pragma unroll
  for (int c = 0; c < 8; ++c)
    h[c] = __floats2half2_rn(src[(size_t)(2*c)*HW_], src[(size_t)(2*c+1)*HW_]);
  uint4* o = reinterpret_cast<uint4*>(dst);
  o[0] = *reinterpret_cast<uint4*>(&h[0]);
  o[1] = *reinterpret_cast<uint4*>(&h[4]);
}

// Fused cost + finalize. Block = 32 pixels x 8 depth-groups (12 bins each).
// res[] held in registers; per-pixel max via LDS; no global re-read.
__global__ __launch_bounds__(256, 4) void fused_kernel(
    const __half* __restrict__ curH, const __half* __restrict__ lookH,
    const float* __restrict__ mats, const float* __restrict__ invK,
    const float* __restrict__ dbins,
    float* __restrict__ cost, float* __restrict__ missing)
{
  int tid = threadIdx.x;
  int pix = tid & (PIX_-1);
  int grp = tid >> 5;                 // 0..7
  int bid = blockIdx.x;
  int chunk = bid % NCHUNK_;
  int b = bid / NCHUNK_;
  int hw = chunk*PIX_ + pix;
  int x = hw % W_, y = hw / W_;
  size_t obase = ((size_t)(b*D_ + grp*BINS_))*HW_ + hw;

  float res[BINS_];
  #pragma unroll
  for (int dd = 0; dd < BINS_; ++dd) res[dd] = 0.f;
  float lmax = 0.f;
  bool interior = (x >= 2 && x < W_-2 && y >= 2 && y < H_-2);
  if (interior) {
    const float* iK = invK + b*16;
    float xf = (float)x, yf = (float)y;
    float r0 = iK[0]*xf + iK[1]*yf + iK[2];
    float r1 = iK[4]*xf + iK[5]*yf + iK[6];
    float r2 = iK[8]*xf + iK[9]*yf + iK[10];
    __half2 cc2[8];
    {
      const uint4* cur4 = reinterpret_cast<const uint4*>(curH + (size_t)(b*HW_ + hw)*C_);
      *reinterpret_cast<uint4*>(&cc2[0]) = cur4[0];
      *reinterpret_cast<uint4*>(&cc2[4]) = cur4[1];
    }
    // wave-uniform projection rows (b uniform per block, f static)
    float Mv[2][13];
    #pragma unroll
    for (int f = 0; f < F_; ++f) {
      const float* Mt = mats + (b*F_+f)*16;
      #pragma unroll
      for (int i = 0; i < 13; ++i) Mv[f][i] = Mt[i];
    }
    #pragma unroll
    for (int dd = 0; dd < BINS_; ++dd) {
      float dep = dbins[grp*BINS_ + dd];
      float p0 = dep*r0, p1 = dep*r1, p2 = dep*r2;
      // --- phase 1: addresses + weights for both frames ---
      const __half* bases[F_];
      float w00f[F_], w10f[F_], w01f[F_], w11f[F_];
      bool okf[F_];
      #pragma unroll
      for (int f = 0; f < F_; ++f) {
        float camx = Mv[f][0]*p0 + Mv[f][1]*p1 + Mv[f][2] *p2 + Mv[f][3];
        float camy = Mv[f][4]*p0 + Mv[f][5]*p1 + Mv[f][6] *p2 + Mv[f][7];
        float camz = Mv[f][8]*p0 + Mv[f][9]*p1 + Mv[f][10]*p2 + Mv[f][11];
        float z  = camz + 1e-7f;
        float px = camx / z;
        float py = camy / z;
        okf[f] = (Mv[f][12] != 0.f) && (px >= 2.f) && (px <= (float)(W_-2))
                                    && (py >= 2.f) && (py <= (float)(H_-2));
        float x0 = floorf(px), y0 = floorf(py);
        float fx = px - x0, fy = py - y0;
        fx = fminf(fmaxf(fx, 0.f), 1.f);
        fy = fminf(fmaxf(fy, 0.f), 1.f);
        int xi = min(max((int)x0, 0), W_-2);
        int yi = min(max((int)y0, 0), H_-2);
        bases[f] = lookH + ((size_t)((b*F_+f)*HW_) + yi*W_ + xi)*C_;
        w00f[f] = (1.f-fx)*(1.f-fy); w10f[f] = fx*(1.f-fy);
        w01f[f] = (1.f-fx)*fy;       w11f[f] = fx*fy;
      }
      // --- phase 2: issue all 16 tap loads ---
      uint4 t[16];
      #pragma unroll
      for (int f = 0; f < F_; ++f) {
        const uint4* rr0 = reinterpret_cast<const uint4*>(bases[f]);
        const uint4* rr1 = reinterpret_cast<const uint4*>(bases[f] + W_*C_);
        #pragma unroll
        for (int i = 0; i < 4; ++i) t[f*8+i]   = rr0[i];
        #pragma unroll
        for (int i = 0; i < 4; ++i) t[f*8+4+i] = rr1[i];
      }
      // --- phase 3: fp16 interpolation + L1 diff ---
      float costsum = 0.f, cnt = 0.f;
      #pragma unroll
      for (int f = 0; f < F_; ++f) {
        __half2 w00h = __float2half2_rn(w00f[f]);
        __half2 w10h = __float2half2_rn(w10f[f]);
        __half2 w01h = __float2half2_rn(w01f[f]);
        __half2 w11h = __float2half2_rn(w11f[f]);
        const __half2* a00 = reinterpret_cast<const __half2*>(&t[f*8+0]);
        const __half2* a10 = reinterpret_cast<const __half2*>(&t[f*8+2]);
        const __half2* a01 = reinterpret_cast<const __half2*>(&t[f*8+4]);
        const __half2* a11 = reinterpret_cast<const __half2*>(&t[f*8+6]);
        __half2 acc0 = __float2half2_rn(0.f);
        __half2 acc1 = __float2half2_rn(0.f);
        #pragma unroll
        for (int i = 0; i < 8; ++i) {
          __half2 v = __hmul2(w00h, a00[i]);
          v = __hfma2(w10h, a10[i], v);
          v = __hfma2(w01h, a01[i], v);
          v = __hfma2(w11h, a11[i], v);
          __half2 dsub = __habs2(__hsub2(v, cc2[i]));
          if (i & 1) acc1 = __hadd2(acc1, dsub);
          else       acc0 = __hadd2(acc0, dsub);
        }
        float2 f0 = __half22float2(acc0);
        float2 f1 = __half22float2(acc1);
        float s = (f0.x + f0.y) + (f1.x + f1.y);
        float diffs = s * (1.f/16.f);
        diffs = okf[f] ? diffs : 0.f;
        costsum += diffs;
        cnt     += (diffs > 0.f) ? 1.f : 0.f;
      }
      float r = costsum / (cnt + 1e-7f);
      res[dd] = r;
      lmax = fmaxf(lmax, r);
    }
  }

  // per-pixel max over the 8 depth-groups
  __shared__ float lmaxs[GRP_][PIX_];
  lmaxs[grp][pix] = lmax;
  __syncthreads();
  float pmax = lmaxs[0][pix];
  #pragma unroll
  for (int g = 1; g < GRP_; ++g) pmax = fmaxf(pmax, lmaxs[g][pix]);

  // write cost (missing-filled) + missing, straight from registers
  #pragma unroll
  for (int dd = 0; dd < BINS_; ++dd) {
    size_t o = obase + (size_t)dd*HW_;
    float v = res[dd];
    float miss = (v == 0.f) ? 1.f : 0.f;
    cost[o]    = miss ? pmax : v;
    missing[o] = miss;
  }
}

extern "C" void kernel_launch(void* const* d_in, const int* in_sizes, int n_in,
                              void* d_out, int out_size, void* d_ws, size_t ws_size,
                              hipStream_t stream) {
  const float* cur   = (const float*)d_in[0];
  const float* look  = (const float*)d_in[1];
  const float* poses = (const float*)d_in[2];
  const float* Km    = (const float*)d_in[3];
  const float* invK  = (const float*)d_in[4];
  const float* dbins = (const float*)d_in[5];

  float* out_cost = (float*)d_out;
  float* out_miss = out_cost + (size_t)B_*D_*HW_;

  char*   ws    = (char*)d_ws;
  float*  mats  = (float*)ws;                                       // 128 floats
  __half* curH  = (__half*)(ws + 1024);                             // B*HW*C f16
  __half* lookH = (__half*)(ws + 1024 + (size_t)B_*HW_*C_*2);       // B*F*HW*C f16

  prep_kernel<<<(B_*HW_ + B_*F_*HW_)/256, 256, 0, stream>>>(
      cur, look, poses, Km, curH, lookH, mats);
  fused_kernel<<<B_*NCHUNK_, 256, 0, stream>>>(
      curH, lookH, mats, invK, dbins, out_cost, out_miss);
}